// Round 6
// baseline (282.611 us; speedup 1.0000x reference)
//
#include <hip/hip_runtime.h>
#include <hip/hip_bf16.h>

// LinearAttention on MI355X. R6 pipeline (peak d_ws 66 MiB):
//  rms_t (fused norm+transpose) -> weight casts ->
//  gemm_bt<1536,split3> (Q->ws, K/V->d_out) ->
//  attn_ctx (context+rowsum -> CTg 2MB) -> attn_out (4 blocks/(b,h), outT->d_out) ->
//  gemm_bt<512,+bias> (bf16 pre->ws) -> rms_final (fused norm+scale, fp32 d_out)
// MFMA = v_mfma_f32_16x16x32_bf16, layouts:
//  A: m=lane&15, k=(lane>>4)*8+j ; B: n=lane&15, k=(lane>>4)*8+j ;
//  C/D: col=lane&15, row=(lane>>4)*4+reg
// gemm LDS XOR swizzle (R5): frag-read conflicts 1.9e7 -> 3.9e5, 74->60 us.

#define AS1 __attribute__((address_space(1)))
#define AS3 __attribute__((address_space(3)))

using short8 = __attribute__((ext_vector_type(8))) short;
using usht4  = __attribute__((ext_vector_type(4))) unsigned short;
using f32x4  = __attribute__((ext_vector_type(4))) float;

__device__ __forceinline__ unsigned short f2bf(float f) {
  unsigned int u = __float_as_uint(f);
  u += 0x7fffu + ((u >> 16) & 1u);          // RNE
  return (unsigned short)(u >> 16);
}
__device__ __forceinline__ float bf2f(unsigned short s) {
  return __uint_as_float(((unsigned int)s) << 16);
}

// ---------------------------------------------------------------------------
// K1: fused rmsnorm factor + transpose.
// X: [32][512][1024] fp32 -> XT: [b][pos][c] bf16 with xn = x * r[b,pos].
// grid (16 pos-tiles, 32 b), 256 thr. Phase A: sumsq (HBM read, f32x4).
// Phase B: per-64c sub-tile re-read (L2-hot) -> LDS f32 -> transposed short8.
__global__ __launch_bounds__(256, 4)
void rms_t(const float* __restrict__ X, unsigned short* __restrict__ XT) {
  __shared__ float partA[16][64];
  __shared__ float rS[64];
  __shared__ float tile[64][65];
  const int t = threadIdx.x;
  const int b = blockIdx.y, pb = blockIdx.x;
  const int pos0 = pb * 64;
  {  // Phase A
    const int pg = t & 15, cq = t >> 4;
    const float* xp = X + ((size_t)b * 512 + (size_t)cq * 32) * 1024 + pos0 + pg * 4;
    f32x4 s = {0.f, 0.f, 0.f, 0.f};
#pragma unroll
    for (int i = 0; i < 32; ++i) {
      f32x4 v = *(const f32x4*)(xp + (size_t)i * 1024);
      s += v * v;
    }
    *(f32x4*)(&partA[cq][pg * 4]) = s;
  }
  __syncthreads();
  if (t < 64) {
    float tot = 0.f;
#pragma unroll
    for (int j = 0; j < 16; ++j) tot += partA[j][t];
    rS[t] = 22.627416998f / fmaxf(sqrtf(tot), 1e-12f);
  }
  __syncthreads();
  // Phase B
  const int p = t & 63, cg = t >> 6;
  const float r = rS[p];
  for (int cb = 0; cb < 8; ++cb) {
    const float* xp = X + ((size_t)b * 512 + (size_t)(cb * 64 + cg * 16)) * 1024 + pos0 + p;
#pragma unroll
    for (int i = 0; i < 16; ++i)
      tile[cg * 16 + i][p] = xp[(size_t)i * 1024] * r;
    __syncthreads();
#pragma unroll
    for (int k = 0; k < 2; ++k) {
      const int idx = k * 256 + t;
      const int p2 = idx >> 3, c8 = idx & 7;
      short8 v;
#pragma unroll
      for (int j = 0; j < 8; ++j) v[j] = (short)f2bf(tile[c8 * 8 + j][p2]);
      *(short8*)(XT + ((size_t)b * 1024 + pos0 + p2) * 512 + cb * 64 + c8 * 8) = v;
    }
    __syncthreads();
  }
}

// ---------------------------------------------------------------------------
// weight casts
__global__ __launch_bounds__(256, 4)
void cast_wqkv(const float* __restrict__ W, const float* __restrict__ g,
               unsigned short* __restrict__ O) {
  int i = blockIdx.x * 256 + threadIdx.x;      // 786432 total
  O[i] = f2bf(W[i] * g[i & 511]);
}
__global__ __launch_bounds__(256, 4)
void cast_w(const float* __restrict__ W, unsigned short* __restrict__ O, int n) {
  int i = blockIdx.x * 256 + threadIdx.x;
  if (i < n) O[i] = f2bf(W[i]);
}

// ---------------------------------------------------------------------------
// Shared GEMM: Out[b][m][n] = sum_k A[m][k]*Ball[b][n][k], bf16 out.
// A: [MTOT][512] bf16 ; Ball: [32][1024][512] bf16. 128x128 tile, BK=64.
// LDS XOR swizzle: LDS[row][pc] holds global chunk (pc ^ (row&7)).
template <int MTOT, bool SPLIT3, bool BIAS>
__global__ __launch_bounds__(256, 2)
void gemm_bt(const unsigned short* __restrict__ A,
             const unsigned short* __restrict__ Ball,
             unsigned short* __restrict__ O0, unsigned short* __restrict__ O1,
             unsigned short* __restrict__ O2, const float* __restrict__ bias) {
  __shared__ char smem[34816];
  unsigned short* lA = (unsigned short*)smem;        // [128][64] swizzled
  unsigned short* lB = lA + 128 * 64;                // [128][64] swizzled
  const int t = threadIdx.x;
  const int lane = t & 63, w = t >> 6;
  const int wm = w >> 1, wn = w & 1;
  const int mt = blockIdx.x >> 3, nt = blockIdx.x & 7;
  const int b = blockIdx.y;
  const unsigned short* Ag = A + (size_t)(mt * 128) * 512;
  const unsigned short* Bg = Ball + ((size_t)b * 1024 + (size_t)nt * 128) * 512;
  const int scol = ((lane & 7) ^ (lane >> 3)) * 8;   // swizzled source chunk
  f32x4 acc[4][4] = {};

  for (int kt = 0; kt < 8; ++kt) {
    const unsigned short* As = Ag + kt * 64 + scol;
    const unsigned short* Bs = Bg + kt * 64 + scol;
#pragma unroll
    for (int i = 0; i < 4; ++i) {
      const int r = w * 32 + i * 8 + (lane >> 3);
      __builtin_amdgcn_global_load_lds(
          (const AS1 unsigned int*)(As + (size_t)r * 512),
          (AS3 unsigned int*)(lA + (w * 32 + i * 8) * 64), 16, 0, 0);
      __builtin_amdgcn_global_load_lds(
          (const AS1 unsigned int*)(Bs + (size_t)r * 512),
          (AS3 unsigned int*)(lB + (w * 32 + i * 8) * 64), 16, 0, 0);
    }
    __syncthreads();
#pragma unroll
    for (int ks = 0; ks < 2; ++ks) {
      const int pch = ((ks * 4 + (lane >> 4)) ^ (lane & 7)) * 8;  // row&7==lane&7
      short8 af[4], bfv[4];
#pragma unroll
      for (int i = 0; i < 4; ++i)
        af[i] = *(const short8*)(lA + (wm * 64 + i * 16 + (lane & 15)) * 64 + pch);
#pragma unroll
      for (int j = 0; j < 4; ++j)
        bfv[j] = *(const short8*)(lB + (wn * 64 + j * 16 + (lane & 15)) * 64 + pch);
#pragma unroll
      for (int i = 0; i < 4; ++i)
#pragma unroll
        for (int j = 0; j < 4; ++j)
          acc[i][j] = __builtin_amdgcn_mfma_f32_16x16x32_bf16(af[i], bfv[j],
                                                              acc[i][j], 0, 0, 0);
    }
    __syncthreads();
  }

  // epilogue: stage bf16 tile in LDS, stream out coalesced 16B stores
  unsigned short* Cst = (unsigned short*)smem;       // [128][136]
#pragma unroll
  for (int i = 0; i < 4; ++i)
#pragma unroll
    for (int j = 0; j < 4; ++j)
#pragma unroll
      for (int r = 0; r < 4; ++r) {
        const int row = wm * 64 + i * 16 + (lane >> 4) * 4 + r;
        const int col = wn * 64 + j * 16 + (lane & 15);
        float v = acc[i][j][r];
        if (BIAS) v += bias[mt * 128 + row];
        Cst[row * 136 + col] = f2bf(v);
      }
  __syncthreads();
  unsigned short* Og;
  if (SPLIT3) {
    const int sec = mt >> 2;
    unsigned short* base = (sec == 0) ? O0 : ((sec == 1) ? O1 : O2);
    Og = base + ((size_t)b * 512 + (size_t)(mt & 3) * 128) * 1024 + (size_t)nt * 128;
  } else {
    Og = O0 + ((size_t)b * MTOT + (size_t)mt * 128) * 1024 + (size_t)nt * 128;
  }
#pragma unroll
  for (int k = 0; k < 8; ++k) {
    const int f = t + k * 256;
    const int row = f >> 4, c8 = f & 15;
    short8 v = *(const short8*)(Cst + row * 136 + c8 * 8);
    *(short8*)(Og + (size_t)row * 1024 + c8 * 8) = v;
  }
}

// ---------------------------------------------------------------------------
// K5a: attention context per (b,h). K/V: [32][512][1024] bf16.
// CTg[bh][e][d] bf16 (64x64 per bh), rowsum 1/sum folded into CT rows (d).
__global__ __launch_bounds__(256, 2)
void attn_ctx(const unsigned short* __restrict__ Kp,
              const unsigned short* __restrict__ Vp,
              const float* __restrict__ memkv,
              unsigned short* __restrict__ CTg) {
  __shared__ unsigned short bufA[64 * 72];   // expK
  __shared__ unsigned short bufB[64 * 72];   // V, then CT
  __shared__ float Pl[512];
  __shared__ float msum[256];
  __shared__ float rsI[64];
  const int t = threadIdx.x;
  const int lane = t & 63, wave = t >> 6;
  const int b = blockIdx.x >> 3, h = blockIdx.x & 7;
  const size_t hb = ((size_t)b * 512 + (size_t)h * 64) * 1024;
  const unsigned short* Kg = Kp + hb;
  const unsigned short* Vg = Vp + hb;
  const float* mk = memkv + (size_t)h * 256;
  const float* mv = memkv + 2048 + (size_t)h * 256;

  float rsum[2] = {0.f, 0.f};
  f32x4 cacc[4] = {};

  // C_raw[d][e] = sum_n exp(K[d][n]) * V[e][n], n over mem(4)+1024
  for (int it = 0; it < 17; ++it) {
    if (it == 0) {                                   // mem tile (cols 0..3, rest 0)
      const int d = t & 63, j = t >> 6;
      const float ev = __expf(mk[d * 4 + j]);
      msum[d * 4 + j] = ev;
      bufA[d * 72 + j] = f2bf(ev);
      bufB[d * 72 + j] = f2bf(mv[d * 4 + j]);
      for (int c2 = 4 + j; c2 < 64; c2 += 4) {
        bufA[d * 72 + c2] = 0;
        bufB[d * 72 + c2] = 0;
      }
    } else {
      const int c0 = (it - 1) * 64;
#pragma unroll
      for (int z = 0; z < 2; ++z) {
        const int d = z * 32 + (t >> 3), ch = t & 7;
        short8 kv = *(const short8*)(Kg + (size_t)d * 1024 + c0 + ch * 8);
        short8 pk;
        float ssum = 0.f;
#pragma unroll
        for (int j = 0; j < 8; ++j) {
          const float e = __expf(bf2f((unsigned short)kv[j]));
          ssum += e;
          pk[j] = (short)f2bf(e);
        }
        rsum[z] += ssum;
        *(short8*)(bufA + d * 72 + ch * 8) = pk;
        short8 vv = *(const short8*)(Vg + (size_t)d * 1024 + c0 + ch * 8);
        *(short8*)(bufB + d * 72 + ch * 8) = vv;
      }
    }
    __syncthreads();
#pragma unroll
    for (int ks = 0; ks < 2; ++ks) {
      short8 a = *(const short8*)(bufA + (wave * 16 + (lane & 15)) * 72 +
                                  ks * 32 + (lane >> 4) * 8);
#pragma unroll
      for (int et = 0; et < 4; ++et) {
        short8 bb = *(const short8*)(bufB + (et * 16 + (lane & 15)) * 72 +
                                     ks * 32 + (lane >> 4) * 8);
        cacc[et] = __builtin_amdgcn_mfma_f32_16x16x32_bf16(a, bb, cacc[et], 0, 0, 0);
      }
    }
    __syncthreads();
  }

  // rowsum reduce: partial for (d, ch) lives at Pl[d*8+ch]
  Pl[t]       = rsum[0];
  Pl[256 + t] = rsum[1];
  __syncthreads();
  if (t < 64) {
    float s = 0.f;
#pragma unroll
    for (int ch = 0; ch < 8; ++ch) s += Pl[t * 8 + ch];
    s += msum[t * 4] + msum[t * 4 + 1] + msum[t * 4 + 2] + msum[t * 4 + 3];
    rsI[t] = 1.0f / s;
  }
  __syncthreads();

  // CT[e][d] = bf16(C_raw[d][e] / rowsum[d]) into LDS, then global
  unsigned short* CT = bufB;                         // staged V is dead
#pragma unroll
  for (int et = 0; et < 4; ++et)
#pragma unroll
    for (int r = 0; r < 4; ++r) {
      const int d = wave * 16 + (lane >> 4) * 4 + r;
      const int e = et * 16 + (lane & 15);
      CT[e * 72 + d] = f2bf(cacc[et][r] * rsI[d]);
    }
  __syncthreads();
#pragma unroll
  for (int k2 = 0; k2 < 2; ++k2) {
    const int idx = k2 * 256 + t;
    const int e = idx >> 3, ch = idx & 7;
    short8 v = *(const short8*)(CT + e * 72 + ch * 8);
    *(short8*)(CTg + (size_t)blockIdx.x * 4096 + e * 64 + ch * 8) = v;
  }
}

// ---------------------------------------------------------------------------
// K5b: attention output. grid 1024 = (b,h) x 4 pos-groups (4 blocks/CU).
// out[e][p] = sum_d CT[e][d]*expQ[d][p] * scale/colsum[p] -> outT[b][p][he].
__global__ __launch_bounds__(256, 4)
void attn_out(const unsigned short* __restrict__ Qp,
              const unsigned short* __restrict__ CTg,
              unsigned short* __restrict__ outT) {
  __shared__ unsigned short bufA[64 * 72];   // expQ^T [p][d]
  __shared__ float Pc[256];
  __shared__ float csS[64];
  const int t = threadIdx.x;
  const int lane = t & 63, wave = t >> 6;
  const int bh = blockIdx.x >> 2, ptq = blockIdx.x & 3;
  const int b = bh >> 3, h = bh & 7;
  const unsigned short* Qg = Qp + ((size_t)b * 512 + (size_t)h * 64) * 1024;

  short8 a0 = *(const short8*)(CTg + (size_t)bh * 4096 +
                               (wave * 16 + (lane & 15)) * 64 + (lane >> 4) * 8);
  short8 a1 = *(const short8*)(CTg + (size_t)bh * 4096 +
                               (wave * 16 + (lane & 15)) * 64 + 32 + (lane >> 4) * 8);
  unsigned short* oBase = outT + (size_t)b * 1024 * 512 + h * 64;

  for (int it = 0; it < 4; ++it) {
    const int pt = ptq * 4 + it;
    {
      const int p = lane, dq = wave;
      float cp = 0.f;
#pragma unroll
      for (int i2 = 0; i2 < 8; ++i2) {
        const int d0 = dq * 16 + i2 * 2;
        const float e0 = __expf(bf2f(Qg[(size_t)d0 * 1024 + pt * 64 + p]));
        const float e1 = __expf(bf2f(Qg[(size_t)(d0 + 1) * 1024 + pt * 64 + p]));
        cp += e0 + e1;
        const unsigned int pk =
            (unsigned int)f2bf(e0) | ((unsigned int)f2bf(e1) << 16);
        *(unsigned int*)(bufA + p * 72 + d0) = pk;   // expQ^T[p][d]
      }
      Pc[dq * 64 + p] = cp;
    }
    __syncthreads();
    if (t < 64) csS[t] = 0.125f / (Pc[t] + Pc[64 + t] + Pc[128 + t] + Pc[192 + t]);
    __syncthreads();
#pragma unroll
    for (int ps = 0; ps < 4; ++ps) {
      f32x4 oc = {};
      short8 b0 = *(const short8*)(bufA + (ps * 16 + (lane & 15)) * 72 + (lane >> 4) * 8);
      short8 b1 = *(const short8*)(bufA + (ps * 16 + (lane & 15)) * 72 + 32 + (lane >> 4) * 8);
      oc = __builtin_amdgcn_mfma_f32_16x16x32_bf16(a0, b0, oc, 0, 0, 0);
      oc = __builtin_amdgcn_mfma_f32_16x16x32_bf16(a1, b1, oc, 0, 0, 0);
      const float cs = csS[ps * 16 + (lane & 15)];
      const unsigned long long pk =
          (unsigned long long)f2bf(oc[0] * cs) |
          ((unsigned long long)f2bf(oc[1] * cs) << 16) |
          ((unsigned long long)f2bf(oc[2] * cs) << 32) |
          ((unsigned long long)f2bf(oc[3] * cs) << 48);
      const int p = pt * 64 + ps * 16 + (lane & 15);
      *(unsigned long long*)(oBase + (size_t)p * 512 + wave * 16 + (lane >> 4) * 4) = pk;
    }
    __syncthreads();
  }
}

// ---------------------------------------------------------------------------
// K8: fused final rmsnorm: out[b][c][p] = bf2f(pre[b][c][p]) * r2[b][p] * g[c]
// pre: [32][512][1024] bf16. grid (16 pos-tiles, 32 b), 256 thr.
__global__ __launch_bounds__(256, 4)
void rms_final(const unsigned short* __restrict__ P,
               const float* __restrict__ G, float* __restrict__ O) {
  __shared__ float partA[16][64];
  __shared__ float rS[64];
  const int t = threadIdx.x;
  const int b = blockIdx.y, pos0 = blockIdx.x * 64;
  const int pg = t & 15, cg = t >> 4;
  const unsigned short* xp =
      P + ((size_t)b * 512 + (size_t)cg * 32) * 1024 + pos0 + pg * 4;
  {
    float s0 = 0.f, s1 = 0.f, s2 = 0.f, s3 = 0.f;
#pragma unroll
    for (int i = 0; i < 32; ++i) {
      usht4 v = *(const usht4*)(xp + (size_t)i * 1024);
      float a = bf2f(v.x), bb = bf2f(v.y), c = bf2f(v.z), d = bf2f(v.w);
      s0 += a * a; s1 += bb * bb; s2 += c * c; s3 += d * d;
    }
    partA[cg][pg * 4 + 0] = s0;
    partA[cg][pg * 4 + 1] = s1;
    partA[cg][pg * 4 + 2] = s2;
    partA[cg][pg * 4 + 3] = s3;
  }
  __syncthreads();
  if (t < 64) {
    float tot = 0.f;
#pragma unroll
    for (int j = 0; j < 16; ++j) tot += partA[j][t];
    rS[t] = 22.627416998f / fmaxf(sqrtf(tot), 1e-12f);
  }
  __syncthreads();
  const float r0 = rS[pg * 4], r1 = rS[pg * 4 + 1], r2 = rS[pg * 4 + 2],
              r3 = rS[pg * 4 + 3];
  float* op = O + ((size_t)b * 512 + (size_t)cg * 32) * 1024 + pos0 + pg * 4;
#pragma unroll
  for (int i = 0; i < 32; ++i) {
    usht4 v = *(const usht4*)(xp + (size_t)i * 1024);   // L2-hot re-read
    const float g = G[cg * 32 + i];
    f32x4 o;
    o.x = bf2f(v.x) * r0 * g;
    o.y = bf2f(v.y) * r1 * g;
    o.z = bf2f(v.z) * r2 * g;
    o.w = bf2f(v.w) * r3 * g;
    *(f32x4*)(op + (size_t)i * 1024) = o;
  }
}

// ---------------------------------------------------------------------------
extern "C" void kernel_launch(void* const* d_in, const int* in_sizes, int n_in,
                              void* d_out, int out_size, void* d_ws, size_t ws_size,
                              hipStream_t stream) {
  (void)in_sizes; (void)n_in; (void)out_size; (void)ws_size;
  const float* x     = (const float*)d_in[0];
  const float* g_in  = (const float*)d_in[1];
  const float* w_qkv = (const float*)d_in[2];
  const float* memkv = (const float*)d_in[3];
  const float* w_out = (const float*)d_in[4];
  const float* b_out = (const float*)d_in[5];
  const float* g_out = (const float*)d_in[6];
  float* out = (float*)d_out;

  // d_ws layout — peak 69,206,016 B (66 MiB)
  char* ws = (char*)d_ws;
  unsigned short* wob = (unsigned short*)ws;               // 0.5 MiB
  unsigned short* wqb = (unsigned short*)(ws + 524288);    // 1.5 MiB
  unsigned short* xnT = (unsigned short*)(ws + 2097152);   // 32 MiB (dead after gemm1)
  unsigned short* CTg = xnT;                               // 2 MiB, aliases dead xnT
  unsigned short* Qp  = (unsigned short*)(ws + 35651584);  // 32 MiB (→ pre)
  unsigned short* pre = Qp;
  // K/V scratch in d_out (64 MiB); outT reuses d_out after ctx consumes K/V.
  unsigned short* Kp   = (unsigned short*)d_out;
  unsigned short* Vp   = (unsigned short*)d_out + 16777216;
  unsigned short* outT = (unsigned short*)d_out;

  rms_t<<<dim3(16, 32), 256, 0, stream>>>(x, xnT);
  cast_wqkv<<<3072, 256, 0, stream>>>(w_qkv, g_in, wqb);
  cast_w<<<1024, 256, 0, stream>>>(w_out, wob, 262144);
  gemm_bt<1536, true, false><<<dim3(96, 32), 256, 0, stream>>>(
      wqb, xnT, Qp, Kp, Vp, nullptr);
  attn_ctx<<<256, 256, 0, stream>>>(Kp, Vp, memkv, CTg);
  attn_out<<<1024, 256, 0, stream>>>(Qp, CTg, outT);
  gemm_bt<512, false, true><<<dim3(32, 32), 256, 0, stream>>>(
      wob, outT, pre, nullptr, nullptr, b_out);
  rms_final<<<dim3(16, 32), 256, 0, stream>>>(pre, g_out, out);
}